// Round 1
// baseline (29.564 us; speedup 1.0000x reference)
//
#include <hip/hip_runtime.h>

#define NATOMS 10000
#define MAXNB  32
#define NRAD   16   // RAD_ORDER 15 -> T_0..T_15
#define NANG   8    // ANG_ORDER 7  -> T_0..T_7
#define WPB    4    // waves (atoms) per 256-thread block

__global__ __launch_bounds__(256, 4) void cheby_desc_kernel(
    const int*   __restrict__ species,   // [N]
    const int*   __restrict__ nb_idx,    // [N, 32]
    const float* __restrict__ nb_vec,    // [N, 32, 3]
    float*       __restrict__ out)       // [N, 48]
{
    const int lane = threadIdx.x & 63;
    const int wv   = threadIdx.x >> 6;
    const int atom = blockIdx.x * WPB + wv;
    const int a    = (atom < NATOMS) ? atom : (NATOMS - 1);
    const int nb   = lane & 31;

    // ---- per-neighbor loads (each neighbor handled by lanes l and l+32) ----
    const float vx = nb_vec[(a * MAXNB + nb) * 3 + 0];
    const float vy = nb_vec[(a * MAXNB + nb) * 3 + 1];
    const float vz = nb_vec[(a * MAXNB + nb) * 3 + 2];
    const int   ni = nb_idx[a * MAXNB + nb];
    const float ts = (float)(2 * species[ni] - 1);   // typespin(2 species) = {-1,+1}

    const float d     = sqrtf(vx * vx + vy * vy + vz * vz);
    const float inv_d = 1.0f / fmaxf(d, 1e-8f);
    const float ux = vx * inv_d, uy = vy * inv_d, uz = vz * inv_d;

    const float PI = 3.14159265358979323846f;

    // ---- radial ----
    float xr = 2.0f * (d - 0.55f) / (6.0f - 0.55f) - 1.0f;
    xr = fminf(fmaxf(xr, -1.0f), 1.0f);
    const float fcr = 0.5f * (cosf(PI * fminf(d, 6.0f) * (1.0f / 6.0f)) + 1.0f);
    float g = ((d <= 6.0f) && (d > 0.55f)) ? fcr : 0.0f;
    if (lane >= 32) g *= ts;   // upper half accumulates typespin-weighted radial

    float rad[NRAD];
    {
        rad[0] = g;
        rad[1] = g * xr;
        float Tp = 1.0f, Tc = xr;
        const float x2 = xr + xr;
        #pragma unroll
        for (int n = 2; n < NRAD; ++n) {
            const float Tn = x2 * Tc - Tp;
            rad[n] = g * Tn;
            Tp = Tc; Tc = Tn;
        }
    }

    // ---- angular per-neighbor quantities ----
    const float fca = ((d <= 4.0f) && (d > 0.55f))
                    ? 0.5f * (cosf(PI * fminf(d, 4.0f) * 0.25f) + 1.0f) : 0.0f;
    const float fcats = fca * ts;   // fold ts into weight: w_ts = (fc ts)_j (fc ts)_k

    __shared__ float nbd[WPB][MAXNB][5];   // stride 5 floats: coprime with 32 banks
    if (lane < 32) {
        nbd[wv][nb][0] = ux;  nbd[wv][nb][1] = uy;  nbd[wv][nb][2] = uz;
        nbd[wv][nb][3] = fca; nbd[wv][nb][4] = fcats;
    }
    __syncthreads();

    // ---- pair loop: circulant enumeration, 8 iters cover all 496 pairs ----
    // pairs (j, (j+o)%32), o=1..16: o in 1..15 hits each unordered pair with
    // circular difference o exactly once; o=16 hits each diff-16 pair twice
    // (halve weight). Lower half-wave takes odd o, upper half even o.
    float aU[NANG], aW[NANG];
    #pragma unroll
    for (int n = 0; n < NANG; ++n) { aU[n] = 0.0f; aW[n] = 0.0f; }

    const int half = lane >> 5;
    #pragma unroll
    for (int it = 0; it < 8; ++it) {
        const int o = 2 * it + 1 + half;
        const int k = (nb + o) & 31;
        const float kx   = nbd[wv][k][0];
        const float ky   = nbd[wv][k][1];
        const float kz   = nbd[wv][k][2];
        const float fk   = nbd[wv][k][3];
        const float fkts = nbd[wv][k][4];
        float c = ux * kx + uy * ky + uz * kz;
        c = fminf(fmaxf(c, -1.0f), 1.0f);
        float w   = fca   * fk;
        float wts = fcats * fkts;
        if (o == 16) { w *= 0.5f; wts *= 0.5f; }
        const float c2 = c + c;
        float Ta = 1.0f, Tb = c;
        aU[0] += w;     aW[0] += wts;
        aU[1] += w * c; aW[1] += wts * c;
        #pragma unroll
        for (int n = 2; n < NANG; ++n) {
            const float Tn = c2 * Tb - Ta;
            aU[n] += w * Tn;  aW[n] += wts * Tn;
            Ta = Tb; Tb = Tn;
        }
    }

    // ---- reductions ----
    #pragma unroll
    for (int n = 0; n < NANG; ++n) {          // full-wave sum (64 lanes)
        float u = aU[n], w = aW[n];
        #pragma unroll
        for (int m = 1; m < 64; m <<= 1) {
            u += __shfl_xor(u, m, 64);
            w += __shfl_xor(w, m, 64);
        }
        aU[n] = u; aW[n] = w;
    }
    #pragma unroll
    for (int n = 0; n < NRAD; ++n) {          // per-half sums: lo=unw, hi=weighted
        float r = rad[n];
        #pragma unroll
        for (int m = 1; m < 32; m <<= 1) r += __shfl_xor(r, m, 64);
        rad[n] = r;
    }

    // ---- stage 48 outputs in LDS, coalesced store ----
    __shared__ float stage[WPB][48];
    if (lane == 0) {
        #pragma unroll
        for (int n = 0; n < NRAD; ++n) stage[wv][n] = rad[n];
        #pragma unroll
        for (int n = 0; n < NANG; ++n) { stage[wv][32 + n] = aU[n]; stage[wv][40 + n] = aW[n]; }
    }
    if (lane == 32) {
        #pragma unroll
        for (int n = 0; n < NRAD; ++n) stage[wv][16 + n] = rad[n];
    }
    __syncthreads();
    if (lane < 48 && atom < NATOMS) out[atom * 48 + lane] = stage[wv][lane];
}

extern "C" void kernel_launch(void* const* d_in, const int* in_sizes, int n_in,
                              void* d_out, int out_size, void* d_ws, size_t ws_size,
                              hipStream_t stream) {
    // setup_inputs order: positions(f32, UNUSED), species_indices(i32),
    //                     neighbor_indices(i32), neighbor_vectors(f32)
    const int*   species = (const int*)  d_in[1];
    const int*   nbidx   = (const int*)  d_in[2];
    const float* nbvec   = (const float*)d_in[3];
    float*       out     = (float*)      d_out;

    const int blocks = (NATOMS + WPB - 1) / WPB;   // 2500
    cheby_desc_kernel<<<blocks, 256, 0, stream>>>(species, nbidx, nbvec, out);
}

// Round 2
// 13.608 us; speedup vs baseline: 2.1725x; 2.1725x over previous
//
#include <hip/hip_runtime.h>

#define NATOMS 10000
#define MAXNB  32
#define NRAD   16   // RAD_ORDER 15 -> T_0..T_15
#define NANG   8    // ANG_ORDER 7  -> T_0..T_7
#define WPB    4    // waves (atoms) per 256-thread block
#define RSTRIDE 33  // odd stride -> worst 2-way LDS bank aliasing (free)

__global__ __launch_bounds__(256, 4) void cheby_desc_kernel(
    const int*   __restrict__ species,   // [N]
    const int*   __restrict__ nb_idx,    // [N, 32]
    const float* __restrict__ nb_vec,    // [N, 32, 3]
    float*       __restrict__ out)       // [N, 48]
{
    const int lane = threadIdx.x & 63;
    const int wv   = threadIdx.x >> 6;
    const int atom = blockIdx.x * WPB + wv;   // 10000 % 4 == 0, always in range
    const int nb   = lane & 31;

    __shared__ float nbd[WPB][MAXNB][5];      // unit xyz, fc_a, fc_a*ts
    __shared__ float red[WPB][64][RSTRIDE];   // per-lane partials for transpose-reduce

    // ---- per-neighbor loads (neighbor nb handled by lanes nb and nb+32) ----
    const float vx = nb_vec[(atom * MAXNB + nb) * 3 + 0];
    const float vy = nb_vec[(atom * MAXNB + nb) * 3 + 1];
    const float vz = nb_vec[(atom * MAXNB + nb) * 3 + 2];
    const int   ni = nb_idx[atom * MAXNB + nb];
    const float ts = (float)(2 * species[ni] - 1);   // typespin(2) = {-1,+1}

    const float d     = __builtin_amdgcn_sqrtf(vx * vx + vy * vy + vz * vz);
    const float inv_d = __builtin_amdgcn_rcpf(fmaxf(d, 1e-8f));
    const float ux = vx * inv_d, uy = vy * inv_d, uz = vz * inv_d;

    const float PI = 3.14159265358979323846f;

    // ---- radial ----
    float xr = 2.0f * (d - 0.55f) * (1.0f / (6.0f - 0.55f)) - 1.0f;
    xr = fminf(fmaxf(xr, -1.0f), 1.0f);
    // bounded arg in [0, pi] -> native v_cos_f32 is accurate to ~1e-6 here
    const float fcr = 0.5f * (__cosf(fminf(d, 6.0f) * (PI / 6.0f)) + 1.0f);
    float g = ((d <= 6.0f) && (d > 0.55f)) ? fcr : 0.0f;
    if (lane >= 32) g *= ts;   // upper half accumulates typespin-weighted radial

    float rad[NRAD];
    {
        rad[0] = g;
        rad[1] = g * xr;
        float Tp = 1.0f, Tc = xr;
        const float x2 = xr + xr;
        #pragma unroll
        for (int n = 2; n < NRAD; ++n) {
            const float Tn = x2 * Tc - Tp;
            rad[n] = g * Tn;
            Tp = Tc; Tc = Tn;
        }
    }

    // ---- angular per-neighbor quantities ----
    const float fca = ((d <= 4.0f) && (d > 0.55f))
                    ? 0.5f * (__cosf(fminf(d, 4.0f) * (PI / 4.0f)) + 1.0f) : 0.0f;
    const float fcats = fca * ts;   // fold ts into weight: w_ts = (fc ts)_j (fc ts)_k

    if (lane < 32) {
        nbd[wv][nb][0] = ux;  nbd[wv][nb][1] = uy;  nbd[wv][nb][2] = uz;
        nbd[wv][nb][3] = fca; nbd[wv][nb][4] = fcats;
    }
    __syncthreads();

    // ---- pair loop: circulant enumeration, 8 iters cover all 496 pairs ----
    // pairs (j,(j+o)&31), o=1..16: o in 1..15 exactly once per unordered pair;
    // o=16 covers each diff-16 pair twice -> halve. Lower half odd o, upper even o.
    float aU[NANG], aW[NANG];
    #pragma unroll
    for (int n = 0; n < NANG; ++n) { aU[n] = 0.0f; aW[n] = 0.0f; }

    const int half = lane >> 5;
    #pragma unroll
    for (int it = 0; it < 8; ++it) {
        const int o = 2 * it + 1 + half;
        const int k = (nb + o) & 31;
        const float kx   = nbd[wv][k][0];
        const float ky   = nbd[wv][k][1];
        const float kz   = nbd[wv][k][2];
        const float fk   = nbd[wv][k][3];
        const float fkts = nbd[wv][k][4];
        float c = ux * kx + uy * ky + uz * kz;
        c = fminf(fmaxf(c, -1.0f), 1.0f);
        float w   = fca   * fk;
        float wts = fcats * fkts;
        if (o == 16) { w *= 0.5f; wts *= 0.5f; }
        const float c2 = c + c;
        float Ta = 1.0f, Tb = c;
        aU[0] += w;     aW[0] += wts;
        aU[1] += w * c; aW[1] += wts * c;
        #pragma unroll
        for (int n = 2; n < NANG; ++n) {
            const float Tn = c2 * Tb - Ta;
            aU[n] += w * Tn;  aW[n] += wts * Tn;
            Ta = Tb; Tb = Tn;
        }
    }

    // ---- transpose-reduce via LDS ----
    // cols 0..15: rad (lower lanes = unweighted, upper = weighted)
    // cols 16..23: aU, cols 24..31: aW (both halves hold disjoint pair subsets)
    {
        float* rrow = &red[wv][lane][0];
        #pragma unroll
        for (int n = 0; n < NRAD; ++n) rrow[n] = rad[n];
        #pragma unroll
        for (int n = 0; n < NANG; ++n) { rrow[16 + n] = aU[n]; rrow[24 + n] = aW[n]; }
    }
    __syncthreads();

    // output lane o: 0..15 rad_unw (sum lanes 0..31), 16..31 rad_w (lanes 32..63),
    // 32..47 ang (lanes 0..31 here; lanes 48..63 sum lanes 32..63, combined below)
    const int   base = ((lane >> 4) & 1) * 32;
    const int   col  = (lane < 32) ? (lane & 15) : (16 + (lane & 15));
    const float* rcol = &red[wv][base][col];
    float s0 = 0.0f, s1 = 0.0f, s2 = 0.0f, s3 = 0.0f;
    #pragma unroll
    for (int i = 0; i < 32; i += 4) {
        s0 += rcol[(i + 0) * RSTRIDE];
        s1 += rcol[(i + 1) * RSTRIDE];
        s2 += rcol[(i + 2) * RSTRIDE];
        s3 += rcol[(i + 3) * RSTRIDE];
    }
    float v = (s0 + s1) + (s2 + s3);
    const float vp = __shfl_xor(v, 16, 64);   // pair ang lanes 32..47 <-> 48..63
    if (lane >= 32) v += vp;
    if (lane < 48) out[atom * 48 + lane] = v;
}

extern "C" void kernel_launch(void* const* d_in, const int* in_sizes, int n_in,
                              void* d_out, int out_size, void* d_ws, size_t ws_size,
                              hipStream_t stream) {
    // setup_inputs order: positions(f32, UNUSED), species_indices(i32),
    //                     neighbor_indices(i32), neighbor_vectors(f32)
    const int*   species = (const int*)  d_in[1];
    const int*   nbidx   = (const int*)  d_in[2];
    const float* nbvec   = (const float*)d_in[3];
    float*       out     = (float*)      d_out;

    const int blocks = NATOMS / WPB;   // 2500
    cheby_desc_kernel<<<blocks, 256, 0, stream>>>(species, nbidx, nbvec, out);
}